// Round 4
// baseline (350.031 us; speedup 1.0000x reference)
//
#include <hip/hip_runtime.h>

typedef unsigned short u16;
typedef unsigned int u32;
typedef __attribute__((ext_vector_type(8))) short short8;   // 8 bf16 (4 VGPRs)
typedef __attribute__((ext_vector_type(4))) float f32x4;

// ws layout (bytes), all 16B-aligned
#define WS_BIAS 0        // float[30*96]
#define WS_W0F 11520     // u16[6*64*8]
#define WS_W1F 17664     // u16[18*64*8]
#define WS_W2F 36096     // u16[18*64*8]

__device__ __forceinline__ u16 f2b(float f) {  // RNE f32 -> bf16
  union { float f; u32 i; } v; v.f = f;
  u32 i = v.i;
  return (u16)((i + 0x7FFFu + ((i >> 16) & 1u)) >> 16);
}

#if __has_builtin(__builtin_amdgcn_cvt_pk_bf16_f32)
__device__ __forceinline__ u32 pk2(float a, float b) {  // 1 VALU op on gfx950
  auto r = __builtin_amdgcn_cvt_pk_bf16_f32(a, b);
  u32 u; __builtin_memcpy(&u, &r, 4); return u;
}
#else
__device__ __forceinline__ u32 pk2(float a, float b) {
  return (u32)f2b(a) | ((u32)f2b(b) << 16);
}
#endif

// Compiler-only memory barrier: DS ops of one wave are processed in order by
// HW (lgkmcnt decrements in-order for pure LDS), so in-wave LDS RAW/WAR needs
// no hardware drain — only protection from compiler reordering. The compiler
// still auto-inserts lgkmcnt waits before using ds_read results.
__device__ __forceinline__ void lds_compiler_fence() {
  asm volatile("" ::: "memory");
}

// Inputs are FP32 storage (bf16-rounded values). Build:
// (1) per-(o,d) layer-1 bias table (augmented unit90 = 1.0), fp32;
// (2) weight fragments (bf16) pre-permuted into MFMA frag order.
// Biases b1/b2 folded in as augmented K-row 90.
__global__ void prep_kernel(const float* __restrict__ ac, const float* __restrict__ W0,
                            const float* __restrict__ b0, const float* __restrict__ W1,
                            const float* __restrict__ b1, const float* __restrict__ W2,
                            const float* __restrict__ b2,
                            float* __restrict__ biasTab, u16* __restrict__ W0f,
                            u16* __restrict__ W1f, u16* __restrict__ W2f) {
  int tid = blockIdx.x * blockDim.x + threadIdx.x;
  int nth = gridDim.x * blockDim.x;
  // biasTab[od][u] = b0[u] + c0*W0[4][u] + c1*W0[6][u];  u==90 -> 1.0 (bias lane)
  for (int i = tid; i < 30 * 96; i += nth) {
    int od = i / 96, u = i % 96;
    float v;
    if (u < 90) {
      float c0 = ac[od * 2 + 0], c1 = ac[od * 2 + 1];
      v = b0[u] + c0 * W0[4 * 90 + u] + c1 * W0[6 * 90 + u];
    } else {
      v = (u == 90) ? 1.0f : 0.0f;
    }
    biasTab[i] = v;
  }
  // W0f: A-operand A[m=unit][k=tap], tap order {xw0..xw4} -> W0 rows {5,0,1,2,3}
  for (int i = tid; i < 6 * 64 * 8; i += nth) {
    int jj = i & 7, lane = (i >> 3) & 63, t = i >> 9;
    int q = lane >> 4, m = lane & 15;
    int k = q * 8 + jj;          // tap within K=32 (only k<5 real)
    int u = t * 16 + m;          // output unit
    u16 v = 0;
    if (k < 5 && u < 90) {
      const int rowmap[5] = {5, 0, 1, 2, 3};
      v = f2b(W0[rowmap[k] * 90 + u]);
    }
    W0f[i] = v;
  }
  // W1f (A-operand, L2) / W2f (B-operand, L3): same (lane,jj)->(k,col) map:
  // value = Waug(k = ki*32 + q*8 + jj, col = t*16 + (lane&15)); row 90 = bias, (90,90)=1
  for (int i = tid; i < 2 * 18 * 64 * 8; i += nth) {
    int which = i / (18 * 64 * 8);
    int j2 = i % (18 * 64 * 8);
    int jj = j2 & 7, lane = (j2 >> 3) & 63, f = j2 >> 9;
    int t = f / 3, ki = f % 3;
    int q = lane >> 4, m = lane & 15;
    int k = ki * 32 + q * 8 + jj;
    int col = t * 16 + m;
    const float* W = which ? W2 : W1;
    const float* bb = which ? b2 : b1;
    u16 v = 0;
    if (k < 90 && col < 90) v = f2b(W[k * 90 + col]);
    else if (k == 90) v = (col < 90) ? f2b(bb[col]) : ((col == 90) ? (u16)0x3F80 : (u16)0);
    (which ? W2f : W1f)[j2] = v;
  }
}

__device__ __forceinline__ f32x4 mfma16(short8 a, short8 b, f32x4 c) {
  return __builtin_amdgcn_mfma_f32_16x16x32_bf16(a, b, c, 0, 0, 0);
}

// One wave = 16 samples (fixed b,o) x 2 tiles, loops d=0..4 accumulating the
// device sum. 1350 blocks x 4 waves x 2 tiles = 10800 tiles, exactly balanced.
// L1: D=A(W0f)*B(x taps). L2: D=A(W1f)*B(h1). L3: D=A(h2)*B(W2f). L4: VALU dot.
// Layer boundary transpose via wave-private LDS row, phi(u=16t+4q+r) = q*24+4t+r.
__global__ __launch_bounds__(256, 4) void mlp_kernel(
    const float* __restrict__ x, const float* __restrict__ W3, const float* __restrict__ b3,
    const float* __restrict__ biasTab, const u16* __restrict__ W0f,
    const u16* __restrict__ W1f, const u16* __restrict__ W2f, float* __restrict__ out) {
  __shared__ u16 H[4][16][104];  // [wave][sample][phi-permuted units], 208B row stride
  const int lane = threadIdx.x & 63;
  const int wv = threadIdx.x >> 6;
  const int q = lane >> 4, n = lane & 15;
  const int w = blockIdx.x * 4 + wv;  // global wave id, 0..5399

  // resident weight fragments (the whole MLP's weights live in VGPRs)
  short8 w0f[6], w1f[6][3], w2f[6][3];
  const short8* p0 = (const short8*)W0f;
  const short8* p1 = (const short8*)W1f;
  const short8* p2 = (const short8*)W2f;
#pragma unroll
  for (int t = 0; t < 6; ++t) w0f[t] = p0[t * 64 + lane];
#pragma unroll
  for (int t = 0; t < 6; ++t)
#pragma unroll
    for (int ki = 0; ki < 3; ++ki) {
      w1f[t][ki] = p1[(t * 3 + ki) * 64 + lane];
      w2f[t][ki] = p2[(t * 3 + ki) * 64 + lane];
    }
  float w3l[6];
#pragma unroll
  for (int t = 0; t < 6; ++t) {
    int u = t * 16 + n;
    w3l[t] = (u < 90) ? W3[u] : ((u == 90) ? b3[0] : 0.0f);  // b3 folded at unit 90
  }

  u16* Hrow = &H[wv][n][0];
  const f32x4 z4 = {0.f, 0.f, 0.f, 0.f};

#pragma unroll 1
  for (int it = 0; it < 2; ++it) {
    int sigma = w * 2 + it;
    int seg = sigma / 225;             // b*6+o
    int l0 = (sigma % 225) * 16;
    int bb = seg / 6, o = seg % 6;
    int l = l0 + n;                    // this lane's sample
    int oh = l / 60, ow = l - oh * 60;
    const float* xrow = x + (bb * 4096 + oh * 64 + ow);

    f32x4 outAcc = {0.f, 0.f, 0.f, 0.f};

    for (int d = 0; d < 5; ++d) {
      // ---- L1: B-frag = x taps (B[k=tap][n=sample]); only q==0 lanes carry taps
      short8 bx = {0, 0, 0, 0, 0, 0, 0, 0};
      if (q == 0) {
        const float* xp = xrow + d * 64;
        bx[0] = (short)f2b(xp[0]); bx[1] = (short)f2b(xp[1]); bx[2] = (short)f2b(xp[2]);
        bx[3] = (short)f2b(xp[3]); bx[4] = (short)f2b(xp[4]);
      }
      f32x4 acc[6];
#pragma unroll
      for (int t = 0; t < 6; ++t) acc[t] = mfma16(w0f[t], bx, z4);

      // bias + relu + pack -> LDS (D layout: col=lane&15=sample, row=q*4+r=unit)
      const float* bt = biasTab + (o * 5 + d) * 96;
#pragma unroll
      for (int t = 0; t < 6; t += 2) {
        f32x4 vA = acc[t] + *(const f32x4*)(bt + t * 16 + q * 4);
        f32x4 vB = acc[t + 1] + *(const f32x4*)(bt + (t + 1) * 16 + q * 4);
        uint4 pk4;
        pk4.x = pk2(fmaxf(vA.x, 0.f), fmaxf(vA.y, 0.f));
        pk4.y = pk2(fmaxf(vA.z, 0.f), fmaxf(vA.w, 0.f));
        pk4.z = pk2(fmaxf(vB.x, 0.f), fmaxf(vB.y, 0.f));
        pk4.w = pk2(fmaxf(vB.z, 0.f), fmaxf(vB.w, 0.f));
        *(uint4*)&Hrow[q * 24 + t * 4] = pk4;
      }
      lds_compiler_fence();  // HW DS is in-order per wave; block compiler reorder only
      short8 F[3];
#pragma unroll
      for (int ki = 0; ki < 3; ++ki) {
        int ph0 = (q & 1) * 48 + (ki * 2 + (q >> 1)) * 4;
        uint2 lo = *(const uint2*)&Hrow[ph0];
        uint2 hi = *(const uint2*)&Hrow[ph0 + 24];
        union { u32 u[4]; short8 s; } fu;
        fu.u[0] = lo.x; fu.u[1] = lo.y; fu.u[2] = hi.x; fu.u[3] = hi.y;
        F[ki] = fu.s;
      }
      lds_compiler_fence();
      // ---- L2: D = W1 * h1
#pragma unroll
      for (int t = 0; t < 6; ++t) {
        f32x4 a = z4;
#pragma unroll
        for (int ki = 0; ki < 3; ++ki) a = mfma16(w1f[t][ki], F[ki], a);
        acc[t] = a;
      }
#pragma unroll
      for (int t = 0; t < 6; t += 2) {
        f32x4 vA = acc[t], vB = acc[t + 1];
        uint4 pk4;
        pk4.x = pk2(fmaxf(vA.x, 0.f), fmaxf(vA.y, 0.f));
        pk4.y = pk2(fmaxf(vA.z, 0.f), fmaxf(vA.w, 0.f));
        pk4.z = pk2(fmaxf(vB.x, 0.f), fmaxf(vB.y, 0.f));
        pk4.w = pk2(fmaxf(vB.z, 0.f), fmaxf(vB.w, 0.f));
        *(uint4*)&Hrow[q * 24 + t * 4] = pk4;
      }
      lds_compiler_fence();
#pragma unroll
      for (int ki = 0; ki < 3; ++ki) {
        int ph0 = (q & 1) * 48 + (ki * 2 + (q >> 1)) * 4;
        uint2 lo = *(const uint2*)&Hrow[ph0];
        uint2 hi = *(const uint2*)&Hrow[ph0 + 24];
        union { u32 u[4]; short8 s; } fu;
        fu.u[0] = lo.x; fu.u[1] = lo.y; fu.u[2] = hi.x; fu.u[3] = hi.y;
        F[ki] = fu.s;
      }
      lds_compiler_fence();
      // ---- L3 (A = h2, B = W2f) + L4 dot with W3 (b3 via unit 90)
#pragma unroll
      for (int t = 0; t < 6; ++t) {
        f32x4 a = z4;
#pragma unroll
        for (int ki = 0; ki < 3; ++ki) a = mfma16(F[ki], w2f[t][ki], a);
        float w3 = w3l[t];
        outAcc.x += fmaxf(a.x, 0.f) * w3;
        outAcc.y += fmaxf(a.y, 0.f) * w3;
        outAcc.z += fmaxf(a.z, 0.f) * w3;
        outAcc.w += fmaxf(a.w, 0.f) * w3;
      }
    }  // d

    // reduce over the 16 unit-lanes (samples live in (q, reg))
#pragma unroll
    for (int off = 1; off < 16; off <<= 1) {
      outAcc.x += __shfl_xor(outAcc.x, off, 64);
      outAcc.y += __shfl_xor(outAcc.y, off, 64);
      outAcc.z += __shfl_xor(outAcc.z, off, 64);
      outAcc.w += __shfl_xor(outAcc.w, off, 64);
    }
    if (n == 0) {
      *(f32x4*)&out[seg * 3600 + l0 + q * 4] = outAcc;  // samples q*4..q*4+3, fp32 out
    }
  }
}

extern "C" void kernel_launch(void* const* d_in, const int* in_sizes, int n_in,
                              void* d_out, int out_size, void* d_ws, size_t ws_size,
                              hipStream_t stream) {
  const float* x  = (const float*)d_in[0];
  const float* ac = (const float*)d_in[1];
  const float* W0 = (const float*)d_in[2];
  const float* b0 = (const float*)d_in[3];
  const float* W1 = (const float*)d_in[4];
  const float* b1 = (const float*)d_in[5];
  const float* W2 = (const float*)d_in[6];
  const float* b2 = (const float*)d_in[7];
  const float* W3 = (const float*)d_in[8];
  const float* b3 = (const float*)d_in[9];
  float* out = (float*)d_out;
  char* ws = (char*)d_ws;
  float* biasTab = (float*)(ws + WS_BIAS);
  u16* W0f = (u16*)(ws + WS_W0F);
  u16* W1f = (u16*)(ws + WS_W1F);
  u16* W2f = (u16*)(ws + WS_W2F);
  prep_kernel<<<64, 256, 0, stream>>>(ac, W0, b0, W1, b1, W2, b2, biasTab, W0f, W1f, W2f);
  mlp_kernel<<<1350, 256, 0, stream>>>(x, W3, b3, biasTab, W0f, W1f, W2f, out);
}

// Round 5
// 135.168 us; speedup vs baseline: 2.5896x; 2.5896x over previous
//
#include <hip/hip_runtime.h>

typedef unsigned short u16;
typedef unsigned int u32;
typedef __attribute__((ext_vector_type(8))) short short8;   // 8 bf16 (4 VGPRs)
typedef __attribute__((ext_vector_type(4))) float f32x4;

// ws layout (bytes), all 16B-aligned
#define WS_BIAS 0        // float[30*96]
#define WS_W0F 11520     // u16[6*64*8]
#define WS_W1F 17664     // u16[18*64*8]
#define WS_W2F 36096     // u16[18*64*8]

__device__ __forceinline__ u16 f2b(float f) {  // RNE f32 -> bf16
  union { float f; u32 i; } v; v.f = f;
  u32 i = v.i;
  return (u16)((i + 0x7FFFu + ((i >> 16) & 1u)) >> 16);
}

#if __has_builtin(__builtin_amdgcn_cvt_pk_bf16_f32)
__device__ __forceinline__ u32 pk2(float a, float b) {  // 1 VALU op on gfx950
  auto r = __builtin_amdgcn_cvt_pk_bf16_f32(a, b);
  u32 u; __builtin_memcpy(&u, &r, 4); return u;
}
#else
__device__ __forceinline__ u32 pk2(float a, float b) {
  return (u32)f2b(a) | ((u32)f2b(b) << 16);
}
#endif

// Compiler-only memory barrier: per-wave DS ops are processed in order by HW,
// so in-wave LDS RAW/WAR needs no hardware drain — only protection from
// compiler reordering. (Verified correct in rounds 3-4: absmax 7.8e-3.)
__device__ __forceinline__ void lds_compiler_fence() {
  asm volatile("" ::: "memory");
}

// Inputs are FP32 storage (bf16-rounded values). Build:
// (1) per-(o,d) layer-1 bias table (augmented unit90 = 1.0), fp32;
// (2) weight fragments (bf16) pre-permuted into MFMA frag order.
// Biases b1/b2 folded in as augmented K-row 90.
__global__ void prep_kernel(const float* __restrict__ ac, const float* __restrict__ W0,
                            const float* __restrict__ b0, const float* __restrict__ W1,
                            const float* __restrict__ b1, const float* __restrict__ W2,
                            const float* __restrict__ b2,
                            float* __restrict__ biasTab, u16* __restrict__ W0f,
                            u16* __restrict__ W1f, u16* __restrict__ W2f) {
  int tid = blockIdx.x * blockDim.x + threadIdx.x;
  int nth = gridDim.x * blockDim.x;
  // biasTab[od][u] = b0[u] + c0*W0[4][u] + c1*W0[6][u];  u==90 -> 1.0 (bias lane)
  for (int i = tid; i < 30 * 96; i += nth) {
    int od = i / 96, u = i % 96;
    float v;
    if (u < 90) {
      float c0 = ac[od * 2 + 0], c1 = ac[od * 2 + 1];
      v = b0[u] + c0 * W0[4 * 90 + u] + c1 * W0[6 * 90 + u];
    } else {
      v = (u == 90) ? 1.0f : 0.0f;
    }
    biasTab[i] = v;
  }
  // W0f: A-operand A[m=unit][k=tap], tap order {xw0..xw4} -> W0 rows {5,0,1,2,3}
  for (int i = tid; i < 6 * 64 * 8; i += nth) {
    int jj = i & 7, lane = (i >> 3) & 63, t = i >> 9;
    int q = lane >> 4, m = lane & 15;
    int k = q * 8 + jj;          // tap within K=32 (only k<5 real)
    int u = t * 16 + m;          // output unit
    u16 v = 0;
    if (k < 5 && u < 90) {
      const int rowmap[5] = {5, 0, 1, 2, 3};
      v = f2b(W0[rowmap[k] * 90 + u]);
    }
    W0f[i] = v;
  }
  // W1f (A-operand, L2) / W2f (B-operand, L3): same (lane,jj)->(k,col) map:
  // value = Waug(k = ki*32 + q*8 + jj, col = t*16 + (lane&15)); row 90 = bias, (90,90)=1
  for (int i = tid; i < 2 * 18 * 64 * 8; i += nth) {
    int which = i / (18 * 64 * 8);
    int j2 = i % (18 * 64 * 8);
    int jj = j2 & 7, lane = (j2 >> 3) & 63, f = j2 >> 9;
    int t = f / 3, ki = f % 3;
    int q = lane >> 4, m = lane & 15;
    int k = ki * 32 + q * 8 + jj;
    int col = t * 16 + m;
    const float* W = which ? W2 : W1;
    const float* bb = which ? b2 : b1;
    u16 v = 0;
    if (k < 90 && col < 90) v = f2b(W[k * 90 + col]);
    else if (k == 90) v = (col < 90) ? f2b(bb[col]) : ((col == 90) ? (u16)0x3F80 : (u16)0);
    (which ? W2f : W1f)[j2] = v;
  }
}

__device__ __forceinline__ f32x4 mfma16(short8 a, short8 b, f32x4 c) {
  return __builtin_amdgcn_mfma_f32_16x16x32_bf16(a, b, c, 0, 0, 0);
}

// One wave = one 16-sample tile (fixed b,o), loops d=0..4 accumulating the
// device sum. 2700 blocks x 4 waves x 1 tile = 10800 tiles, perfectly balanced.
// launch_bounds (256,2): VGPR cap 256 — compiler uses ~124, NO spill. (256,4)
// capped VGPRs at 64 and spilled the resident weights to scratch: 565 MB HBM
// traffic, 4x slower. Occupancy comes from grid size, not the bounds arg.
__global__ __launch_bounds__(256, 2) void mlp_kernel(
    const float* __restrict__ x, const float* __restrict__ W3, const float* __restrict__ b3,
    const float* __restrict__ biasTab, const u16* __restrict__ W0f,
    const u16* __restrict__ W1f, const u16* __restrict__ W2f, float* __restrict__ out) {
  __shared__ u16 H[4][16][104];  // [wave][sample][phi-permuted units], 208B row stride
  const int lane = threadIdx.x & 63;
  const int wv = threadIdx.x >> 6;
  const int q = lane >> 4, n = lane & 15;
  const int w = blockIdx.x * 4 + wv;  // global wave id = tile id, 0..10799

  // resident weight fragments (the whole MLP's weights live in VGPRs)
  short8 w0f[6], w1f[6][3], w2f[6][3];
  const short8* p0 = (const short8*)W0f;
  const short8* p1 = (const short8*)W1f;
  const short8* p2 = (const short8*)W2f;
#pragma unroll
  for (int t = 0; t < 6; ++t) w0f[t] = p0[t * 64 + lane];
#pragma unroll
  for (int t = 0; t < 6; ++t)
#pragma unroll
    for (int ki = 0; ki < 3; ++ki) {
      w1f[t][ki] = p1[(t * 3 + ki) * 64 + lane];
      w2f[t][ki] = p2[(t * 3 + ki) * 64 + lane];
    }
  float w3l[6];
#pragma unroll
  for (int t = 0; t < 6; ++t) {
    int u = t * 16 + n;
    w3l[t] = (u < 90) ? W3[u] : ((u == 90) ? b3[0] : 0.0f);  // b3 folded at unit 90
  }

  u16* Hrow = &H[wv][n][0];
  const f32x4 z4 = {0.f, 0.f, 0.f, 0.f};

  const int sigma = w;
  const int seg = sigma / 225;             // b*6+o
  const int l0 = (sigma % 225) * 16;
  const int bb = seg / 6, o = seg % 6;
  const int l = l0 + n;                    // this lane's sample
  const int oh = l / 60, ow = l - oh * 60;
  const float* xrow = x + (bb * 4096 + oh * 64 + ow);

  f32x4 outAcc = {0.f, 0.f, 0.f, 0.f};

  for (int d = 0; d < 5; ++d) {
    // ---- L1: B-frag = x taps (B[k=tap][n=sample]); only q==0 lanes carry taps
    short8 bx = {0, 0, 0, 0, 0, 0, 0, 0};
    if (q == 0) {
      const float* xp = xrow + d * 64;
      bx[0] = (short)f2b(xp[0]); bx[1] = (short)f2b(xp[1]); bx[2] = (short)f2b(xp[2]);
      bx[3] = (short)f2b(xp[3]); bx[4] = (short)f2b(xp[4]);
    }
    f32x4 acc[6];
#pragma unroll
    for (int t = 0; t < 6; ++t) acc[t] = mfma16(w0f[t], bx, z4);

    // bias + relu + pack -> LDS (D layout: col=lane&15=sample, row=q*4+r=unit)
    const float* bt = biasTab + (o * 5 + d) * 96;
#pragma unroll
    for (int t = 0; t < 6; t += 2) {
      f32x4 vA = acc[t] + *(const f32x4*)(bt + t * 16 + q * 4);
      f32x4 vB = acc[t + 1] + *(const f32x4*)(bt + (t + 1) * 16 + q * 4);
      uint4 pk4;
      pk4.x = pk2(fmaxf(vA.x, 0.f), fmaxf(vA.y, 0.f));
      pk4.y = pk2(fmaxf(vA.z, 0.f), fmaxf(vA.w, 0.f));
      pk4.z = pk2(fmaxf(vB.x, 0.f), fmaxf(vB.y, 0.f));
      pk4.w = pk2(fmaxf(vB.z, 0.f), fmaxf(vB.w, 0.f));
      *(uint4*)&Hrow[q * 24 + t * 4] = pk4;
    }
    lds_compiler_fence();
    short8 F[3];
#pragma unroll
    for (int ki = 0; ki < 3; ++ki) {
      int ph0 = (q & 1) * 48 + (ki * 2 + (q >> 1)) * 4;
      uint2 lo = *(const uint2*)&Hrow[ph0];
      uint2 hi = *(const uint2*)&Hrow[ph0 + 24];
      union { u32 u[4]; short8 s; } fu;
      fu.u[0] = lo.x; fu.u[1] = lo.y; fu.u[2] = hi.x; fu.u[3] = hi.y;
      F[ki] = fu.s;
    }
    lds_compiler_fence();
    // ---- L2: D = W1 * h1
#pragma unroll
    for (int t = 0; t < 6; ++t) {
      f32x4 a = z4;
#pragma unroll
      for (int ki = 0; ki < 3; ++ki) a = mfma16(w1f[t][ki], F[ki], a);
      acc[t] = a;
    }
#pragma unroll
    for (int t = 0; t < 6; t += 2) {
      f32x4 vA = acc[t], vB = acc[t + 1];
      uint4 pk4;
      pk4.x = pk2(fmaxf(vA.x, 0.f), fmaxf(vA.y, 0.f));
      pk4.y = pk2(fmaxf(vA.z, 0.f), fmaxf(vA.w, 0.f));
      pk4.z = pk2(fmaxf(vB.x, 0.f), fmaxf(vB.y, 0.f));
      pk4.w = pk2(fmaxf(vB.z, 0.f), fmaxf(vB.w, 0.f));
      *(uint4*)&Hrow[q * 24 + t * 4] = pk4;
    }
    lds_compiler_fence();
#pragma unroll
    for (int ki = 0; ki < 3; ++ki) {
      int ph0 = (q & 1) * 48 + (ki * 2 + (q >> 1)) * 4;
      uint2 lo = *(const uint2*)&Hrow[ph0];
      uint2 hi = *(const uint2*)&Hrow[ph0 + 24];
      union { u32 u[4]; short8 s; } fu;
      fu.u[0] = lo.x; fu.u[1] = lo.y; fu.u[2] = hi.x; fu.u[3] = hi.y;
      F[ki] = fu.s;
    }
    lds_compiler_fence();
    // ---- L3 (A = h2, B = W2f) + L4 dot with W3 (b3 via unit 90)
#pragma unroll
    for (int t = 0; t < 6; ++t) {
      f32x4 a = z4;
#pragma unroll
      for (int ki = 0; ki < 3; ++ki) a = mfma16(F[ki], w2f[t][ki], a);
      float w3 = w3l[t];
      outAcc.x += fmaxf(a.x, 0.f) * w3;
      outAcc.y += fmaxf(a.y, 0.f) * w3;
      outAcc.z += fmaxf(a.z, 0.f) * w3;
      outAcc.w += fmaxf(a.w, 0.f) * w3;
    }
  }  // d

  // reduce over the 16 unit-lanes (samples live in (q, reg))
#pragma unroll
  for (int off = 1; off < 16; off <<= 1) {
    outAcc.x += __shfl_xor(outAcc.x, off, 64);
    outAcc.y += __shfl_xor(outAcc.y, off, 64);
    outAcc.z += __shfl_xor(outAcc.z, off, 64);
    outAcc.w += __shfl_xor(outAcc.w, off, 64);
  }
  if (n == 0) {
    *(f32x4*)&out[seg * 3600 + l0 + q * 4] = outAcc;  // samples q*4..q*4+3, fp32 out
  }
}

extern "C" void kernel_launch(void* const* d_in, const int* in_sizes, int n_in,
                              void* d_out, int out_size, void* d_ws, size_t ws_size,
                              hipStream_t stream) {
  const float* x  = (const float*)d_in[0];
  const float* ac = (const float*)d_in[1];
  const float* W0 = (const float*)d_in[2];
  const float* b0 = (const float*)d_in[3];
  const float* W1 = (const float*)d_in[4];
  const float* b1 = (const float*)d_in[5];
  const float* W2 = (const float*)d_in[6];
  const float* b2 = (const float*)d_in[7];
  const float* W3 = (const float*)d_in[8];
  const float* b3 = (const float*)d_in[9];
  float* out = (float*)d_out;
  char* ws = (char*)d_ws;
  float* biasTab = (float*)(ws + WS_BIAS);
  u16* W0f = (u16*)(ws + WS_W0F);
  u16* W1f = (u16*)(ws + WS_W1F);
  u16* W2f = (u16*)(ws + WS_W2F);
  prep_kernel<<<128, 256, 0, stream>>>(ac, W0, b0, W1, b1, W2, b2, biasTab, W0f, W1f, W2f);
  mlp_kernel<<<2700, 256, 0, stream>>>(x, W3, b3, biasTab, W0f, W1f, W2f, out);
}

// Round 6
// 127.619 us; speedup vs baseline: 2.7428x; 1.0592x over previous
//
#include <hip/hip_runtime.h>

typedef unsigned short u16;
typedef unsigned int u32;
typedef __attribute__((ext_vector_type(8))) short short8;   // 8 bf16 (4 VGPRs)
typedef __attribute__((ext_vector_type(4))) float f32x4;

// ws layout (bytes), all 16B-aligned
#define WS_BIAS 0        // float[30*96]
#define WS_W3T  11520    // float[96]   (W3 augmented: [90]=b3, [91..95]=0)
#define WS_W0F  11904    // u16[6*64*8]
#define WS_W1F  18048    // u16[18*64*8]
#define WS_W2F  36480    // u16[18*64*8]   (ends 54912)

__device__ __forceinline__ u16 f2b(float f) {  // RNE f32 -> bf16
  union { float f; u32 i; } v; v.f = f;
  u32 i = v.i;
  return (u16)((i + 0x7FFFu + ((i >> 16) & 1u)) >> 16);
}

#if __has_builtin(__builtin_amdgcn_cvt_pk_bf16_f32)
__device__ __forceinline__ u32 pk2(float a, float b) {  // 1 VALU op on gfx950
  auto r = __builtin_amdgcn_cvt_pk_bf16_f32(a, b);
  u32 u; __builtin_memcpy(&u, &r, 4); return u;
}
#else
__device__ __forceinline__ u32 pk2(float a, float b) {
  return (u32)f2b(a) | ((u32)f2b(b) << 16);
}
#endif

// Inputs are FP32 storage (bf16-rounded values).
// Key trick: the K-dimension label of a GEMM is arbitrary. We permute the
// K-rows of W1/W2 at prep time with unit(q,j) = 32ki + 16*(j>>2) + 4q + (j&3)
// so that each lane's next-layer B-fragment is exactly its OWN 4 accumulator
// registers relu'd+packed — no LDS transpose, no shuffles, no fences.
__global__ void prep_kernel(const float* __restrict__ ac, const float* __restrict__ W0,
                            const float* __restrict__ b0, const float* __restrict__ W1,
                            const float* __restrict__ b1, const float* __restrict__ W2,
                            const float* __restrict__ b2, const float* __restrict__ W3,
                            const float* __restrict__ b3,
                            float* __restrict__ biasTab, float* __restrict__ w3t,
                            u16* __restrict__ W0f, u16* __restrict__ W1f,
                            u16* __restrict__ W2f) {
  int tid = blockIdx.x * blockDim.x + threadIdx.x;
  int nth = gridDim.x * blockDim.x;
  // biasTab[od][u] = b0[u] + c0*W0[4][u] + c1*W0[6][u];  u==90 -> 1.0 (bias lane)
  for (int i = tid; i < 30 * 96; i += nth) {
    int od = i / 96, u = i % 96;
    float v;
    if (u < 90) {
      float c0 = ac[od * 2 + 0], c1 = ac[od * 2 + 1];
      v = b0[u] + c0 * W0[4 * 90 + u] + c1 * W0[6 * 90 + u];
    } else {
      v = (u == 90) ? 1.0f : 0.0f;
    }
    biasTab[i] = v;
  }
  // w3t: augmented W3 (unit 90 carries b3)
  for (int i = tid; i < 96; i += nth)
    w3t[i] = (i < 90) ? W3[i] : ((i == 90) ? b3[0] : 0.0f);
  // W0f: A-operand A[m=unit][k=tap], standard K; tap order {xw0..xw4} -> W0 rows {5,0,1,2,3}
  for (int i = tid; i < 6 * 64 * 8; i += nth) {
    int jj = i & 7, lane = (i >> 3) & 63, t = i >> 9;
    int q = lane >> 4, m = lane & 15;
    int k = q * 8 + jj;          // tap within K=32 (only k<5 real; other quads zero)
    int u = t * 16 + m;          // output unit
    u16 v = 0;
    if (k < 5 && u < 90) {
      const int rowmap[5] = {5, 0, 1, 2, 3};
      v = f2b(W0[rowmap[k] * 90 + u]);
    }
    W0f[i] = v;
  }
  // W1f/W2f: A-operands with PERMUTED K so D-layout feeds B directly.
  // slot (qA, jA) of frag ki holds Waug row 32ki + 16*(jA>>2) + 4qA + (jA&3),
  // col = 16t + m.  Row 90 = bias row, (90,90)=1 (propagates the "1" unit).
  for (int i = tid; i < 2 * 18 * 64 * 8; i += nth) {
    int which = i / (18 * 64 * 8);
    int j2 = i % (18 * 64 * 8);
    int jj = j2 & 7, lane = (j2 >> 3) & 63, f = j2 >> 9;
    int t = f / 3, ki = f % 3;
    int qA = lane >> 4, m = lane & 15;
    int row = 32 * ki + 16 * (jj >> 2) + 4 * qA + (jj & 3);
    int col = 16 * t + m;
    const float* W = which ? W2 : W1;
    const float* bb = which ? b2 : b1;
    u16 v = 0;
    if (row < 90 && col < 90) v = f2b(W[row * 90 + col]);
    else if (row == 90) v = (col < 90) ? f2b(bb[col]) : ((col == 90) ? (u16)0x3F80 : (u16)0);
    (which ? W2f : W1f)[j2] = v;
  }
}

__device__ __forceinline__ f32x4 mfma16(short8 a, short8 b, f32x4 c) {
  return __builtin_amdgcn_mfma_f32_16x16x32_bf16(a, b, c, 0, 0, 0);
}

// relu+pack one acc pair into a B-fragment (the lane's own registers — the
// K-permutation baked into W1f/W2f makes this layout-exact).
__device__ __forceinline__ short8 packB(const f32x4& a0, const f32x4& a1) {
  union { u32 u[4]; short8 s; } fu;
  fu.u[0] = pk2(fmaxf(a0.x, 0.f), fmaxf(a0.y, 0.f));
  fu.u[1] = pk2(fmaxf(a0.z, 0.f), fmaxf(a0.w, 0.f));
  fu.u[2] = pk2(fmaxf(a1.x, 0.f), fmaxf(a1.y, 0.f));
  fu.u[3] = pk2(fmaxf(a1.z, 0.f), fmaxf(a1.w, 0.f));
  return fu.s;
}

// One wave = one 16-sample tile (fixed b,o), d=0..4 accumulated in registers.
// Zero LDS. L1: A=W0f,B=taps,C=bias. L2: A=W1f(permK),B=pack(h1).
// L3: A=W2f(permK),B=pack(h2). L4: per-lane dot with w3v + cross-quad reduce.
__global__ __launch_bounds__(256, 2) void mlp_kernel(
    const float* __restrict__ x, const float* __restrict__ biasTab,
    const float* __restrict__ w3t, const u16* __restrict__ W0f,
    const u16* __restrict__ W1f, const u16* __restrict__ W2f,
    float* __restrict__ out) {
  const int lane = threadIdx.x & 63;
  const int wv = threadIdx.x >> 6;
  const int q = lane >> 4, n = lane & 15;
  const int w = blockIdx.x * 4 + wv;  // tile id, 0..10799

  // resident weights (~196 regs incl. w3v; total wave usage ~250 — 2 waves/SIMD)
  short8 w0f[6], w1f[6][3], w2f[6][3];
  const short8* p0 = (const short8*)W0f;
  const short8* p1 = (const short8*)W1f;
  const short8* p2 = (const short8*)W2f;
#pragma unroll
  for (int t = 0; t < 6; ++t) w0f[t] = p0[t * 64 + lane];
#pragma unroll
  for (int t = 0; t < 6; ++t)
#pragma unroll
    for (int ki = 0; ki < 3; ++ki) {
      w1f[t][ki] = p1[(t * 3 + ki) * 64 + lane];
      w2f[t][ki] = p2[(t * 3 + ki) * 64 + lane];
    }
  f32x4 w3v[6];
#pragma unroll
  for (int t = 0; t < 6; ++t) w3v[t] = *(const f32x4*)(w3t + t * 16 + q * 4);

  const int seg = w / 225;             // b*6+o
  const int l0 = (w % 225) * 16;
  const int bb = seg / 6, o = seg % 6;
  const int l = l0 + n;                // this lane's sample
  const int oh = l / 60, ow = l - oh * 60;
  const float* xrow = x + (bb * 4096 + oh * 64 + ow);

  const f32x4 z4 = {0.f, 0.f, 0.f, 0.f};
  float outAcc = 0.f;

  for (int d = 0; d < 5; ++d) {
    // taps (all lanes; quads 1-3 multiply against zeroed W0f rows)
    const float* xp = xrow + d * 64;
    short8 bx = {0, 0, 0, 0, 0, 0, 0, 0};
    bx[0] = (short)f2b(xp[0]); bx[1] = (short)f2b(xp[1]); bx[2] = (short)f2b(xp[2]);
    bx[3] = (short)f2b(xp[3]); bx[4] = (short)f2b(xp[4]);

    // ---- L1 (bias as C-operand)
    const float* bt = biasTab + (o * 5 + d) * 96;
    f32x4 acc[6];
#pragma unroll
    for (int t = 0; t < 6; ++t)
      acc[t] = mfma16(w0f[t], bx, *(const f32x4*)(bt + t * 16 + q * 4));

    // ---- pack h1 (in-register; K-permutation makes this the exact B-frag)
    short8 h[3];
#pragma unroll
    for (int ki = 0; ki < 3; ++ki) h[ki] = packB(acc[2 * ki], acc[2 * ki + 1]);

    // ---- L2
#pragma unroll
    for (int t = 0; t < 6; ++t) {
      f32x4 a = z4;
#pragma unroll
      for (int ki = 0; ki < 3; ++ki) a = mfma16(w1f[t][ki], h[ki], a);
      acc[t] = a;
    }
#pragma unroll
    for (int ki = 0; ki < 3; ++ki) h[ki] = packB(acc[2 * ki], acc[2 * ki + 1]);

    // ---- L3 (D rows = output units) + L4 dot with augmented W3
#pragma unroll
    for (int t = 0; t < 6; ++t) {
      f32x4 a = z4;
#pragma unroll
      for (int ki = 0; ki < 3; ++ki) a = mfma16(w2f[t][ki], h[ki], a);
      outAcc += fmaxf(a.x, 0.f) * w3v[t].x + fmaxf(a.y, 0.f) * w3v[t].y +
                fmaxf(a.z, 0.f) * w3v[t].z + fmaxf(a.w, 0.f) * w3v[t].w;
    }
  }  // d

  // reduce the 4 quad-partials per sample column
  outAcc += __shfl_xor(outAcc, 16, 64);
  outAcc += __shfl_xor(outAcc, 32, 64);
  if (lane < 16) out[seg * 3600 + l0 + lane] = outAcc;
}

extern "C" void kernel_launch(void* const* d_in, const int* in_sizes, int n_in,
                              void* d_out, int out_size, void* d_ws, size_t ws_size,
                              hipStream_t stream) {
  const float* x  = (const float*)d_in[0];
  const float* ac = (const float*)d_in[1];
  const float* W0 = (const float*)d_in[2];
  const float* b0 = (const float*)d_in[3];
  const float* W1 = (const float*)d_in[4];
  const float* b1 = (const float*)d_in[5];
  const float* W2 = (const float*)d_in[6];
  const float* b2 = (const float*)d_in[7];
  const float* W3 = (const float*)d_in[8];
  const float* b3 = (const float*)d_in[9];
  float* out = (float*)d_out;
  char* ws = (char*)d_ws;
  float* biasTab = (float*)(ws + WS_BIAS);
  float* w3t = (float*)(ws + WS_W3T);
  u16* W0f = (u16*)(ws + WS_W0F);
  u16* W1f = (u16*)(ws + WS_W1F);
  u16* W2f = (u16*)(ws + WS_W2F);
  prep_kernel<<<128, 256, 0, stream>>>(ac, W0, b0, W1, b1, W2, b2, W3, b3,
                                       biasTab, w3t, W0f, W1f, W2f);
  mlp_kernel<<<2700, 256, 0, stream>>>(x, biasTab, w3t, W0f, W1f, W2f, out);
}

// Round 7
// 122.793 us; speedup vs baseline: 2.8506x; 1.0393x over previous
//
#include <hip/hip_runtime.h>

typedef unsigned short u16;
typedef unsigned int u32;
typedef __attribute__((ext_vector_type(8))) short short8;   // 8 bf16 (4 VGPRs)
typedef __attribute__((ext_vector_type(4))) float f32x4;

// ws layout (bytes), all 16B-aligned
#define WS_BIAS 0        // float[30*96]
#define WS_W3T  11520    // float[96]   (W3 augmented: [90]=b3, [91..95]=0)
#define WS_W0F  11904    // u16[6*64*8]
#define WS_W1F  18048    // u16[18*64*8]
#define WS_W2F  36480    // u16[18*64*8]   (ends 54912)

__device__ __forceinline__ u16 f2b(float f) {  // RNE f32 -> bf16 (prep only)
  union { float f; u32 i; } v; v.f = f;
  u32 i = v.i;
  return (u16)((i + 0x7FFFu + ((i >> 16) & 1u)) >> 16);
}

// 3-op bf16 pair pack: round-half-up (+0x8000) then v_perm_b32 grabs the two
// high halves. R4-R6 evidence: __builtin_amdgcn_cvt_pk_bf16_f32 doesn't exist
// here (VALU cycles never moved), so the old path was an 11-op RNE fallback —
// the dominant VALU consumer (~80k cyc/SIMD, identical R3 vs R6).
// __builtin_amdgcn_perm(hi, lo, sel): sel 0x07060302 -> {hi[31:16], lo[31:16]}.
__device__ __forceinline__ u32 pk2(float a, float b) {  // a -> low half, b -> high
  u32 ia = __float_as_uint(a) + 0x8000u;
  u32 ib = __float_as_uint(b) + 0x8000u;
  return __builtin_amdgcn_perm(ib, ia, 0x07060302u);
}

// Inputs are FP32 storage (bf16-rounded values).
// Key trick: the K-dimension label of a GEMM is arbitrary. We permute the
// K-rows of W1/W2 at prep time with unit(q,j) = 32ki + 16*(j>>2) + 4q + (j&3)
// so that each lane's next-layer B-fragment is exactly its OWN 4 accumulator
// registers relu'd+packed — no LDS transpose, no shuffles, no fences.
__global__ void prep_kernel(const float* __restrict__ ac, const float* __restrict__ W0,
                            const float* __restrict__ b0, const float* __restrict__ W1,
                            const float* __restrict__ b1, const float* __restrict__ W2,
                            const float* __restrict__ b2, const float* __restrict__ W3,
                            const float* __restrict__ b3,
                            float* __restrict__ biasTab, float* __restrict__ w3t,
                            u16* __restrict__ W0f, u16* __restrict__ W1f,
                            u16* __restrict__ W2f) {
  int tid = blockIdx.x * blockDim.x + threadIdx.x;
  int nth = gridDim.x * blockDim.x;
  // biasTab[od][u] = b0[u] + c0*W0[4][u] + c1*W0[6][u];  u==90 -> 1.0 (bias lane)
  for (int i = tid; i < 30 * 96; i += nth) {
    int od = i / 96, u = i % 96;
    float v;
    if (u < 90) {
      float c0 = ac[od * 2 + 0], c1 = ac[od * 2 + 1];
      v = b0[u] + c0 * W0[4 * 90 + u] + c1 * W0[6 * 90 + u];
    } else {
      v = (u == 90) ? 1.0f : 0.0f;
    }
    biasTab[i] = v;
  }
  // w3t: augmented W3 (unit 90 carries b3)
  for (int i = tid; i < 96; i += nth)
    w3t[i] = (i < 90) ? W3[i] : ((i == 90) ? b3[0] : 0.0f);
  // W0f: A-operand A[m=unit][k=tap], standard K; tap order {xw0..xw4} -> W0 rows {5,0,1,2,3}
  for (int i = tid; i < 6 * 64 * 8; i += nth) {
    int jj = i & 7, lane = (i >> 3) & 63, t = i >> 9;
    int q = lane >> 4, m = lane & 15;
    int k = q * 8 + jj;          // tap within K=32 (only k<5 real; other quads zero)
    int u = t * 16 + m;          // output unit
    u16 v = 0;
    if (k < 5 && u < 90) {
      const int rowmap[5] = {5, 0, 1, 2, 3};
      v = f2b(W0[rowmap[k] * 90 + u]);
    }
    W0f[i] = v;
  }
  // W1f/W2f: A-operands with PERMUTED K so D-layout feeds B directly.
  // slot (qA, jA) of frag ki holds Waug row 32ki + 16*(jA>>2) + 4qA + (jA&3),
  // col = 16t + m.  Row 90 = bias row, (90,90)=1 (propagates the "1" unit).
  for (int i = tid; i < 2 * 18 * 64 * 8; i += nth) {
    int which = i / (18 * 64 * 8);
    int j2 = i % (18 * 64 * 8);
    int jj = j2 & 7, lane = (j2 >> 3) & 63, f = j2 >> 9;
    int t = f / 3, ki = f % 3;
    int qA = lane >> 4, m = lane & 15;
    int row = 32 * ki + 16 * (jj >> 2) + 4 * qA + (jj & 3);
    int col = 16 * t + m;
    const float* W = which ? W2 : W1;
    const float* bb = which ? b2 : b1;
    u16 v = 0;
    if (row < 90 && col < 90) v = f2b(W[row * 90 + col]);
    else if (row == 90) v = (col < 90) ? f2b(bb[col]) : ((col == 90) ? (u16)0x3F80 : (u16)0);
    (which ? W2f : W1f)[j2] = v;
  }
}

__device__ __forceinline__ f32x4 mfma16(short8 a, short8 b, f32x4 c) {
  return __builtin_amdgcn_mfma_f32_16x16x32_bf16(a, b, c, 0, 0, 0);
}

// relu+pack one acc pair into a B-fragment: 8 v_max + 4x3 pack = 20 VALU ops.
__device__ __forceinline__ short8 packB(const f32x4& a0, const f32x4& a1) {
  union { u32 u[4]; short8 s; } fu;
  fu.u[0] = pk2(fmaxf(a0.x, 0.f), fmaxf(a0.y, 0.f));
  fu.u[1] = pk2(fmaxf(a0.z, 0.f), fmaxf(a0.w, 0.f));
  fu.u[2] = pk2(fmaxf(a1.x, 0.f), fmaxf(a1.y, 0.f));
  fu.u[3] = pk2(fmaxf(a1.z, 0.f), fmaxf(a1.w, 0.f));
  return fu.s;
}

// One wave = one 16-sample tile (fixed b,o), d=0..4 accumulated in registers.
// Zero LDS. L1: A=W0f,B=taps,C=bias. L2: A=W1f(permK),B=pack(h1).
// L3: A=W2f(permK),B=pack(h2). L4: per-lane dot with w3v + cross-quad reduce.
__global__ __launch_bounds__(256, 2) void mlp_kernel(
    const float* __restrict__ x, const float* __restrict__ biasTab,
    const float* __restrict__ w3t, const u16* __restrict__ W0f,
    const u16* __restrict__ W1f, const u16* __restrict__ W2f,
    float* __restrict__ out) {
  const int lane = threadIdx.x & 63;
  const int wv = threadIdx.x >> 6;
  const int q = lane >> 4, n = lane & 15;
  const int w = blockIdx.x * 4 + wv;  // tile id, 0..10799

  // resident weights
  short8 w0f[6], w1f[6][3], w2f[6][3];
  const short8* p0 = (const short8*)W0f;
  const short8* p1 = (const short8*)W1f;
  const short8* p2 = (const short8*)W2f;
#pragma unroll
  for (int t = 0; t < 6; ++t) w0f[t] = p0[t * 64 + lane];
#pragma unroll
  for (int t = 0; t < 6; ++t)
#pragma unroll
    for (int ki = 0; ki < 3; ++ki) {
      w1f[t][ki] = p1[(t * 3 + ki) * 64 + lane];
      w2f[t][ki] = p2[(t * 3 + ki) * 64 + lane];
    }
  f32x4 w3v[6];
#pragma unroll
  for (int t = 0; t < 6; ++t) w3v[t] = *(const f32x4*)(w3t + t * 16 + q * 4);

  const int seg = w / 225;             // b*6+o
  const int l0 = (w % 225) * 16;
  const int bb = seg / 6, o = seg % 6;
  const int l = l0 + n;                // this lane's sample
  const int oh = l / 60, ow = l - oh * 60;
  const float* xrow = x + (bb * 4096 + oh * 64 + ow);

  const f32x4 z4 = {0.f, 0.f, 0.f, 0.f};
  float outAcc = 0.f;

  for (int d = 0; d < 5; ++d) {
    // taps: 5 scalar loads + 3 pk2 assembling the B-frag dwords directly
    // (quads 1-3 multiply against zeroed W0f rows, content irrelevant there)
    const float* xp = xrow + d * 64;
    union { u32 u[4]; short8 s; } bu;
    bu.u[0] = pk2(xp[0], xp[1]);
    bu.u[1] = pk2(xp[2], xp[3]);
    bu.u[2] = pk2(xp[4], 0.0f);
    bu.u[3] = 0;
    short8 bx = bu.s;

    // ---- L1 (bias as C-operand)
    const float* bt = biasTab + (o * 5 + d) * 96;
    f32x4 acc[6];
#pragma unroll
    for (int t = 0; t < 6; ++t)
      acc[t] = mfma16(w0f[t], bx, *(const f32x4*)(bt + t * 16 + q * 4));

    // ---- pack h1 (in-register; K-permutation makes this the exact B-frag)
    short8 h[3];
#pragma unroll
    for (int ki = 0; ki < 3; ++ki) h[ki] = packB(acc[2 * ki], acc[2 * ki + 1]);

    // ---- L2
#pragma unroll
    for (int t = 0; t < 6; ++t) {
      f32x4 a = z4;
#pragma unroll
      for (int ki = 0; ki < 3; ++ki) a = mfma16(w1f[t][ki], h[ki], a);
      acc[t] = a;
    }
#pragma unroll
    for (int ki = 0; ki < 3; ++ki) h[ki] = packB(acc[2 * ki], acc[2 * ki + 1]);

    // ---- L3 (D rows = output units) + L4 dot with augmented W3
#pragma unroll
    for (int t = 0; t < 6; ++t) {
      f32x4 a = z4;
#pragma unroll
      for (int ki = 0; ki < 3; ++ki) a = mfma16(w2f[t][ki], h[ki], a);
      outAcc += fmaxf(a.x, 0.f) * w3v[t].x + fmaxf(a.y, 0.f) * w3v[t].y +
                fmaxf(a.z, 0.f) * w3v[t].z + fmaxf(a.w, 0.f) * w3v[t].w;
    }
  }  // d

  // reduce the 4 quad-partials per sample column
  outAcc += __shfl_xor(outAcc, 16, 64);
  outAcc += __shfl_xor(outAcc, 32, 64);
  if (lane < 16) out[seg * 3600 + l0 + lane] = outAcc;
}

extern "C" void kernel_launch(void* const* d_in, const int* in_sizes, int n_in,
                              void* d_out, int out_size, void* d_ws, size_t ws_size,
                              hipStream_t stream) {
  const float* x  = (const float*)d_in[0];
  const float* ac = (const float*)d_in[1];
  const float* W0 = (const float*)d_in[2];
  const float* b0 = (const float*)d_in[3];
  const float* W1 = (const float*)d_in[4];
  const float* b1 = (const float*)d_in[5];
  const float* W2 = (const float*)d_in[6];
  const float* b2 = (const float*)d_in[7];
  const float* W3 = (const float*)d_in[8];
  const float* b3 = (const float*)d_in[9];
  float* out = (float*)d_out;
  char* ws = (char*)d_ws;
  float* biasTab = (float*)(ws + WS_BIAS);
  float* w3t = (float*)(ws + WS_W3T);
  u16* W0f = (u16*)(ws + WS_W0F);
  u16* W1f = (u16*)(ws + WS_W1F);
  u16* W2f = (u16*)(ws + WS_W2F);
  prep_kernel<<<128, 256, 0, stream>>>(ac, W0, b0, W1, b1, W2, b2, W3, b3,
                                       biasTab, w3t, W0f, W1f, W2f);
  mlp_kernel<<<2700, 256, 0, stream>>>(x, biasTab, w3t, W0f, W1f, W2f, out);
}

// Round 8
// 121.698 us; speedup vs baseline: 2.8762x; 1.0090x over previous
//
#include <hip/hip_runtime.h>

typedef unsigned short u16;
typedef unsigned int u32;
typedef __attribute__((ext_vector_type(8))) short short8;   // 8 bf16 (4 VGPRs)
typedef __attribute__((ext_vector_type(4))) float f32x4;

// ws layout (bytes), all 16B-aligned
#define WS_W3T  0        // float[96]  (W3 augmented: [90]=b3, [91..95]=0)
#define WS_W0F  384      // u16[6][6*64*8]  per-o L1 fragments w/ bias rows k=5..9
#define WS_W1F  37248    // u16[18*64*8]
#define WS_W2F  55680    // u16[18*64*8]   (ends 74112)

__device__ __forceinline__ u16 f2b(float f) {  // RNE f32 -> bf16 (prep only)
  union { float f; u32 i; } v; v.f = f;
  u32 i = v.i;
  return (u16)((i + 0x7FFFu + ((i >> 16) & 1u)) >> 16);
}

// 3-op bf16 pair pack (round-half-up + v_perm). Verified R7: -18k VALU cyc/SIMD.
__device__ __forceinline__ u32 pk2(float a, float b) {  // a -> low half, b -> high
  u32 ia = __float_as_uint(a) + 0x8000u;
  u32 ib = __float_as_uint(b) + 0x8000u;
  return __builtin_amdgcn_perm(ib, ia, 0x07060302u);
}

// Inputs are FP32 storage (bf16-rounded values).
// L1 trick (new): K=32 had only 5 live tap slots. Slots k=5..9 become a
// one-hot(d) selector and W0f (per output-channel o) carries the five
// per-(o,d) bias rows; row k=5+d, col 90 is 1.0 for every d so the
// augmented "1" unit still enters h1. L1's C-operand is then zero —
// no per-iteration bias loads at all.
// W1/W2 keep the permuted-K layout (lane's own acc = next B-frag).
__global__ void prep_kernel(const float* __restrict__ ac, const float* __restrict__ W0,
                            const float* __restrict__ b0, const float* __restrict__ W1,
                            const float* __restrict__ b1, const float* __restrict__ W2,
                            const float* __restrict__ b2, const float* __restrict__ W3,
                            const float* __restrict__ b3,
                            float* __restrict__ w3t, u16* __restrict__ W0f,
                            u16* __restrict__ W1f, u16* __restrict__ W2f) {
  int tid = blockIdx.x * blockDim.x + threadIdx.x;
  int nth = gridDim.x * blockDim.x;
  // w3t: augmented W3 (unit 90 carries b3)
  for (int i = tid; i < 96; i += nth)
    w3t[i] = (i < 90) ? W3[i] : ((i == 90) ? b3[0] : 0.0f);
  // W0f[o][t][lane][jj]: A[m=unit][k]; k<5: taps (W0 rows {5,0,1,2,3});
  // k=5+dd: bias row for device dd of channel o; (k=5+dd, u=90) = 1.0.
  for (int i = tid; i < 6 * 6 * 64 * 8; i += nth) {
    int o = i / 3072, rem = i % 3072;
    int t = rem >> 9, lane = (rem >> 3) & 63, jj = rem & 7;
    int q = lane >> 4, m = lane & 15;
    int k = q * 8 + jj;
    int u = t * 16 + m;
    u16 v = 0;
    if (k < 5) {
      const int rowmap[5] = {5, 0, 1, 2, 3};
      if (u < 90) v = f2b(W0[rowmap[k] * 90 + u]);
    } else if (k < 10) {
      int dd = k - 5;
      if (u < 90) {
        float c0 = ac[(o * 5 + dd) * 2 + 0], c1 = ac[(o * 5 + dd) * 2 + 1];
        v = f2b(b0[u] + c0 * W0[4 * 90 + u] + c1 * W0[6 * 90 + u]);
      } else if (u == 90) {
        v = (u16)0x3F80;  // the "1" unit
      }
    }
    W0f[i] = v;
  }
  // W1f/W2f: A-operands with PERMUTED K so D-layout feeds B directly.
  // slot (qA, jA) of frag ki holds Waug row 32ki + 16*(jA>>2) + 4qA + (jA&3),
  // col = 16t + m.  Row 90 = bias row, (90,90)=1 (propagates the "1" unit).
  for (int i = tid; i < 2 * 18 * 64 * 8; i += nth) {
    int which = i / (18 * 64 * 8);
    int j2 = i % (18 * 64 * 8);
    int jj = j2 & 7, lane = (j2 >> 3) & 63, f = j2 >> 9;
    int t = f / 3, ki = f % 3;
    int qA = lane >> 4, m = lane & 15;
    int row = 32 * ki + 16 * (jj >> 2) + 4 * qA + (jj & 3);
    int col = 16 * t + m;
    const float* W = which ? W2 : W1;
    const float* bb = which ? b2 : b1;
    u16 v = 0;
    if (row < 90 && col < 90) v = f2b(W[row * 90 + col]);
    else if (row == 90) v = (col < 90) ? f2b(bb[col]) : ((col == 90) ? (u16)0x3F80 : (u16)0);
    (which ? W2f : W1f)[j2] = v;
  }
}

__device__ __forceinline__ f32x4 mfma16(short8 a, short8 b, f32x4 c) {
  return __builtin_amdgcn_mfma_f32_16x16x32_bf16(a, b, c, 0, 0, 0);
}

// relu+pack one acc pair into a B-fragment: 8 v_max + 4x3 pack.
__device__ __forceinline__ short8 packB(const f32x4& a0, const f32x4& a1) {
  union { u32 u[4]; short8 s; } fu;
  fu.u[0] = pk2(fmaxf(a0.x, 0.f), fmaxf(a0.y, 0.f));
  fu.u[1] = pk2(fmaxf(a0.z, 0.f), fmaxf(a0.w, 0.f));
  fu.u[2] = pk2(fmaxf(a1.x, 0.f), fmaxf(a1.y, 0.f));
  fu.u[3] = pk2(fmaxf(a1.z, 0.f), fmaxf(a1.w, 0.f));
  return fu.s;
}

// One wave = TWO 16-sample tiles {w, w+5400} (same o, same l0, batch+4),
// flattened (tile,d) loop of 10 iters with tap prefetch. Zero LDS, zero
// in-loop VMEM except the 5 prefetched tap floats.
__global__ __launch_bounds__(256, 2) void mlp_kernel(
    const float* __restrict__ x, const float* __restrict__ w3t,
    const u16* __restrict__ W0f, const u16* __restrict__ W1f,
    const u16* __restrict__ W2f, float* __restrict__ out) {
  const int lane = threadIdx.x & 63;
  const int wv = threadIdx.x >> 6;
  const int q = lane >> 4, n = lane & 15;
  const int w = blockIdx.x * 4 + wv;  // 0..5399; tiles {w, w+5400}

  const int seg0 = w / 225;            // b*6+o   (tile1: seg0+24, same o)
  const int l0 = (w % 225) * 16;
  const int bb0 = seg0 / 6, o = seg0 % 6;

  // resident weights (w0f from this wave's o-variant)
  short8 w0f[6], w1f[6][3], w2f[6][3];
  const short8* p0 = (const short8*)W0f + o * 384;
  const short8* p1 = (const short8*)W1f;
  const short8* p2 = (const short8*)W2f;
#pragma unroll
  for (int t = 0; t < 6; ++t) w0f[t] = p0[t * 64 + lane];
#pragma unroll
  for (int t = 0; t < 6; ++t)
#pragma unroll
    for (int ki = 0; ki < 3; ++ki) {
      w1f[t][ki] = p1[(t * 3 + ki) * 64 + lane];
      w2f[t][ki] = p2[(t * 3 + ki) * 64 + lane];
    }
  f32x4 w3v[6];
#pragma unroll
  for (int t = 0; t < 6; ++t) w3v[t] = *(const f32x4*)(w3t + t * 16 + q * 4);

  const int l = l0 + n;
  const int oh = l / 60, ow = l - oh * 60;
  const float* xrow0 = x + (bb0 * 4096 + oh * 64 + ow);
  const float* xrow1 = xrow0 + 4 * 4096;  // batch +4

  const f32x4 z4 = {0.f, 0.f, 0.f, 0.f};
  float outAcc0 = 0.f, outAcc1 = 0.f;

  // prefetch taps for j=0
  float pa0 = xrow0[0], pa1 = xrow0[1], pa2 = xrow0[2], pa3 = xrow0[3], pa4 = xrow0[4];

#pragma unroll 1
  for (int j = 0; j < 10; ++j) {
    float c0 = pa0, c1 = pa1, c2 = pa2, c3 = pa3, c4 = pa4;
    int jn = j + 1;
    if (jn < 10) {  // issue next iter's tap loads now; consumed next iter
      const float* xp = (jn < 5) ? (xrow0 + jn * 64) : (xrow1 + (jn - 5) * 64);
      pa0 = xp[0]; pa1 = xp[1]; pa2 = xp[2]; pa3 = xp[3]; pa4 = xp[4];
    }
    const int d = (j < 5) ? j : j - 5;

    // one-hot(d) bias-selector slots k=5..9 (wave-uniform constants -> SALU)
    const u32 u3c = (d == 1) ? 0x00003F80u : ((d == 2) ? 0x3F800000u : 0u);  // k6,k7
    const u32 q1c = (d == 3) ? 0x00003F80u : ((d == 4) ? 0x3F800000u : 0u);  // k8,k9
    const float k5f = (d == 0) ? 1.0f : 0.0f;                                // k5

    union { u32 u[4]; short8 s; } bu;
    u32 t01 = pk2(c0, c1);
    bu.u[0] = (q == 1) ? q1c : t01;  // q0: taps k0,k1; q1: one-hot k8,k9
    bu.u[1] = pk2(c2, c3);           // q0: k2,k3 (other quads hit zero rows)
    bu.u[2] = pk2(c4, k5f);          // q0: k4 + one-hot k5
    bu.u[3] = u3c;                   // q0: k6,k7
    short8 bx = bu.s;

    // ---- L1 (C = 0; bias rides W0f rows 5..9 via the one-hot)
    f32x4 acc[6];
#pragma unroll
    for (int t = 0; t < 6; ++t) acc[t] = mfma16(w0f[t], bx, z4);

    short8 h[3];
#pragma unroll
    for (int ki = 0; ki < 3; ++ki) h[ki] = packB(acc[2 * ki], acc[2 * ki + 1]);

    // ---- L2
#pragma unroll
    for (int t = 0; t < 6; ++t) {
      f32x4 a = z4;
#pragma unroll
      for (int ki = 0; ki < 3; ++ki) a = mfma16(w1f[t][ki], h[ki], a);
      acc[t] = a;
    }
#pragma unroll
    for (int ki = 0; ki < 3; ++ki) h[ki] = packB(acc[2 * ki], acc[2 * ki + 1]);

    // ---- L3 + L4 dot with augmented W3
    float r = 0.f;
#pragma unroll
    for (int t = 0; t < 6; ++t) {
      f32x4 a = z4;
#pragma unroll
      for (int ki = 0; ki < 3; ++ki) a = mfma16(w2f[t][ki], h[ki], a);
      r += fmaxf(a.x, 0.f) * w3v[t].x + fmaxf(a.y, 0.f) * w3v[t].y +
           fmaxf(a.z, 0.f) * w3v[t].z + fmaxf(a.w, 0.f) * w3v[t].w;
    }
    if (j < 5) outAcc0 += r; else outAcc1 += r;
  }

  // reduce quad-partials and store both tiles
  outAcc0 += __shfl_xor(outAcc0, 16, 64);
  outAcc0 += __shfl_xor(outAcc0, 32, 64);
  outAcc1 += __shfl_xor(outAcc1, 16, 64);
  outAcc1 += __shfl_xor(outAcc1, 32, 64);
  if (lane < 16) {
    out[seg0 * 3600 + l0 + lane] = outAcc0;
    out[(seg0 + 24) * 3600 + l0 + lane] = outAcc1;
  }
}

extern "C" void kernel_launch(void* const* d_in, const int* in_sizes, int n_in,
                              void* d_out, int out_size, void* d_ws, size_t ws_size,
                              hipStream_t stream) {
  const float* x  = (const float*)d_in[0];
  const float* ac = (const float*)d_in[1];
  const float* W0 = (const float*)d_in[2];
  const float* b0 = (const float*)d_in[3];
  const float* W1 = (const float*)d_in[4];
  const float* b1 = (const float*)d_in[5];
  const float* W2 = (const float*)d_in[6];
  const float* b2 = (const float*)d_in[7];
  const float* W3 = (const float*)d_in[8];
  const float* b3 = (const float*)d_in[9];
  float* out = (float*)d_out;
  char* ws = (char*)d_ws;
  float* w3t = (float*)(ws + WS_W3T);
  u16* W0f = (u16*)(ws + WS_W0F);
  u16* W1f = (u16*)(ws + WS_W1F);
  u16* W2f = (u16*)(ws + WS_W2F);
  prep_kernel<<<128, 256, 0, stream>>>(ac, W0, b0, W1, b1, W2, b2, W3, b3,
                                       w3t, W0f, W1f, W2f);
  mlp_kernel<<<1350, 256, 0, stream>>>(x, w3t, W0f, W1f, W2f, out);
}